// Round 8
// baseline (413.597 us; speedup 1.0000x reference)
//
#include <hip/hip_runtime.h>

#define F 128
#define TILE 48
#define NTHR 512
#define NBLK 256

typedef __attribute__((ext_vector_type(8))) __bf16 bf16x8;
typedef __attribute__((ext_vector_type(4))) float f32x4;
typedef __attribute__((ext_vector_type(8))) unsigned short us8;
typedef __attribute__((ext_vector_type(4))) unsigned short us4;
typedef __attribute__((ext_vector_type(2))) unsigned short us2;

struct f3 { float x, y, z; };   // 12B -> global_store_dwordx3

__device__ __forceinline__ unsigned short f2bf(float x) {
    __bf16 h = (__bf16)x;                       // HW v_cvt (RNE)
    return __builtin_bit_cast(unsigned short, h);
}
__device__ __forceinline__ float bf2f(unsigned short u) {
    unsigned x = ((unsigned)u) << 16;
    return __builtin_bit_cast(float, x);
}
__device__ __forceinline__ bf16x8 pack8(float4 a, float4 b) {
    us8 t;
    t[0] = f2bf(a.x); t[1] = f2bf(a.y); t[2] = f2bf(a.z); t[3] = f2bf(a.w);
    t[4] = f2bf(b.x); t[5] = f2bf(b.y); t[6] = f2bf(b.z); t[7] = f2bf(b.w);
    return __builtin_bit_cast(bf16x8, t);
}

// async global->LDS, 16B per lane; lds base wave-uniform
__device__ __forceinline__ void gload16(const float* g, const unsigned short* l) {
    __builtin_amdgcn_global_load_lds(
        (const __attribute__((address_space(1))) void*)g,
        (__attribute__((address_space(3))) void*)l, 16, 0, 0);
}

// LDS map (ushort units), 74496 sh = 148992 B -> 1 block/CU
#define RAWV 0        // 36864 sh : raw f32 v tile (48x128x3), linear
#define VRB  36864    // 18432 sh : v bf16, 144 rows (crow=c*48+nl) x 128, XOR-swizzled
#define A2B  55296    // 12672 sh : 48 x 264  (s bf16 | ||Vv||^2 bf16)
#define A2S  264
#define A3B  67968    //  6528 sh : 48 x 136  (h bf16)
#define A3S  136
#define SHSZ 74496

// VR addressing (ushort index) with (row&7)<<3 XOR swizzle -> 2-way banks only
__device__ __forceinline__ int vr_idx(int crow, int k) {
    return VRB + (((crow << 7) + k) ^ ((crow & 7) << 3));
}

__global__ __launch_bounds__(256)
void prep_w(const float* __restrict__ Uw, const float* __restrict__ Vw,
            const float* __restrict__ aw1, const float* __restrict__ aw2,
            unsigned short* __restrict__ wbf)
{
    int i = (blockIdx.x * 256 + threadIdx.x) * 4;   // grid 112x256 covers 114688
    const float* src; int off;
    if (i < 16384)      { src = Uw;  off = i; }
    else if (i < 32768) { src = Vw;  off = i - 16384; }
    else if (i < 65536) { src = aw1; off = i - 32768; }
    else                { src = aw2; off = i - 65536; }
    float4 x = *(const float4*)&src[off];
    us4 o;
    o[0] = f2bf(x.x); o[1] = f2bf(x.y); o[2] = f2bf(x.z); o[3] = f2bf(x.w);
    *(us4*)&wbf[i] = o;
}

template<bool PRE>
__global__ __launch_bounds__(NTHR) __attribute__((amdgpu_waves_per_eu(2, 2)))
void painn_main(const float* __restrict__ s, const float* __restrict__ v,
                const float* __restrict__ Uw, const float* __restrict__ Vw,
                const float* __restrict__ aw1, const float* __restrict__ ab1,
                const float* __restrict__ aw2, const float* __restrict__ ab2,
                const unsigned short* __restrict__ wbf,
                float* __restrict__ out, int Ntot)
{
    __shared__ __align__(16) unsigned short SH[SHSZ];

    const int tid  = threadIdx.x;
    const int lane = tid & 63;
    const int w    = tid >> 6;        // wave 0..7
    const int l15  = lane & 15;
    const int kp   = lane >> 4;       // 0..3
    const int col  = (w << 4) | l15;  // output column 0..127
    const size_t NF = (size_t)Ntot * F;
    const int NT   = (Ntot + TILE - 1) / TILE;          // 2084 (tail tile: 16 rows)
    const size_t vmax = (size_t)Ntot * 384 - 256;       // clamp for async src

    const unsigned short* wU  = wbf;
    const unsigned short* wV  = wbf + 16384;
    const unsigned short* wW1 = wbf + 32768;
    const unsigned short* wW2 = wbf + 65536;

    const float b1  = ab1[col];
    const float bss = ab2[col];
    const float bsv = ab2[F + col];
    const float bvv = ab2[2 * F + col];

    const float* rawv = (const float*)&SH[RAWV];
    float4 sreg[3];   // s rows for current tile (prefetched one iter ahead)

    // ---- prologue: asyncs + s for first tile; one-time full drain ----
    {
        int t0 = blockIdx.x;
        #pragma unroll
        for (int j = 0; j < 9; ++j) {
            size_t ofs = (size_t)t0 * 18432 + (w + j * 8) * 256;
            if (ofs > vmax) ofs = vmax;
            gload16(v + ofs + lane * 4, &SH[RAWV + (size_t)(w + j * 8) * 512]);
        }
        #pragma unroll
        for (int it = 0; it < 3; ++it) {
            int idx = tid + it * 512;
            int row = idx >> 5;
            int f0  = (idx & 31) << 2;
            int gr  = t0 * TILE + row; if (gr >= Ntot) gr = Ntot - 1;
            sreg[it] = *(const float4*)&s[(size_t)gr * 128 + f0];
        }
    }
    asm volatile("s_waitcnt vmcnt(0)" ::: "memory");

    for (int t = blockIdx.x; t < NT; t += NBLK) {
        // B0: own asyncs done (16 tolerates epilogue stores; first iter pre-drained)
        asm volatile("s_waitcnt vmcnt(16)" ::: "memory");
        __builtin_amdgcn_s_barrier();

        // ---- cluster1: bU,bV,bW1 — issued BEFORE this iter's asyncs ----
        bf16x8 bU[4], bV[4], bW1[8];
        #pragma unroll
        for (int ks = 0; ks < 4; ++ks) {
            int k0 = (ks << 5) + (kp << 3);
            if constexpr (PRE) {
                bU[ks] = *(const bf16x8*)&wU[col * F + k0];
                bV[ks] = *(const bf16x8*)&wV[col * F + k0];
            } else {
                const float4* pu = (const float4*)&Uw[col * F + k0];
                bU[ks] = pack8(pu[0], pu[1]);
                const float4* pv = (const float4*)&Vw[col * F + k0];
                bV[ks] = pack8(pv[0], pv[1]);
            }
        }
        #pragma unroll
        for (int ks = 0; ks < 8; ++ks) {
            int k0 = (ks << 5) + (kp << 3);
            if constexpr (PRE) {
                bW1[ks] = *(const bf16x8*)&wW1[col * 256 + k0];
            } else {
                const float4* p = (const float4*)&aw1[col * 256 + k0];
                bW1[ks] = pack8(p[0], p[1]);
            }
        }
        __builtin_amdgcn_sched_barrier(0);

        // ---- convert: raw f32 -> VR (bf16, c-major, swizzled); sreg -> A2 ----
        #pragma unroll
        for (int it = 0; it < 6; ++it) {
            int idx = tid + it * 512;         // 3072 tasks: 48 rows x 64 f-pairs
            int nl  = idx >> 6;
            int f0  = (idx & 63) << 1;
            const float2* src = (const float2*)&rawv[nl * 384 + f0 * 3];
            float2 ab = src[0], cd = src[1], ef = src[2];
            us2 p;
            p[0] = f2bf(ab.x); p[1] = f2bf(cd.y); *(us2*)&SH[vr_idx(0 * TILE + nl, f0)] = p;
            p[0] = f2bf(ab.y); p[1] = f2bf(ef.x); *(us2*)&SH[vr_idx(1 * TILE + nl, f0)] = p;
            p[0] = f2bf(cd.x); p[1] = f2bf(ef.y); *(us2*)&SH[vr_idx(2 * TILE + nl, f0)] = p;
        }
        #pragma unroll
        for (int it = 0; it < 3; ++it) {
            int idx = tid + it * 512;
            int row = idx >> 5;
            int f0  = (idx & 31) << 2;
            us4 t0;
            t0[0] = f2bf(sreg[it].x); t0[1] = f2bf(sreg[it].y);
            t0[2] = f2bf(sreg[it].z); t0[3] = f2bf(sreg[it].w);
            *(us4*)&SH[A2B + row * A2S + f0] = t0;
        }
        asm volatile("s_waitcnt lgkmcnt(0)" ::: "memory");
        __builtin_amdgcn_s_barrier();       // B1: VR + A2 s-half ready; raw free

        // ---- asyncs + s prefetch for t+NBLK (fire-and-forget) ----
        if (t + NBLK < NT) {
            int t2 = t + NBLK;
            #pragma unroll
            for (int j = 0; j < 9; ++j) {
                size_t ofs = (size_t)t2 * 18432 + (w + j * 8) * 256;
                if (ofs > vmax) ofs = vmax;
                gload16(v + ofs + lane * 4, &SH[RAWV + (size_t)(w + j * 8) * 512]);
            }
            #pragma unroll
            for (int it = 0; it < 3; ++it) {
                int idx = tid + it * 512;
                int row = idx >> 5;
                int f0  = (idx & 31) << 2;
                int gr  = t2 * TILE + row; if (gr >= Ntot) gr = Ntot - 1;
                sreg[it] = *(const float4*)&s[(size_t)gr * 128 + f0];
            }
        }
        __builtin_amdgcn_sched_barrier(0);

        // ---- stage 1: Uv, Vv per-c passes (72 MFMAs/wave) ----
        float nrm[3][4], inr[3][4];
        us4 pU[9];
        #pragma unroll
        for (int c = 0; c < 3; ++c) {
            f32x4 aU[3], aV[3];
            #pragma unroll
            for (int nt = 0; nt < 3; ++nt) { aU[nt] = (f32x4){0.f,0.f,0.f,0.f}; aV[nt] = (f32x4){0.f,0.f,0.f,0.f}; }
            #pragma unroll
            for (int ks = 0; ks < 4; ++ks) {
                #pragma unroll
                for (int nt = 0; nt < 3; ++nt) {
                    int crow = c * TILE + nt * 16 + l15;
                    bf16x8 a = *(const bf16x8*)&SH[vr_idx(crow, (ks << 5) + (kp << 3))];
                    aU[nt] = __builtin_amdgcn_mfma_f32_16x16x32_bf16(a, bU[ks], aU[nt], 0, 0, 0);
                    aV[nt] = __builtin_amdgcn_mfma_f32_16x16x32_bf16(a, bV[ks], aV[nt], 0, 0, 0);
                }
            }
            #pragma unroll
            for (int nt = 0; nt < 3; ++nt) {
                us4 q;
                #pragma unroll
                for (int r = 0; r < 4; ++r) {
                    float uu = aU[nt][r], vv = aV[nt][r];
                    if (c == 0) { nrm[nt][r] = vv * vv; inr[nt][r] = uu * vv; }
                    else        { nrm[nt][r] += vv * vv; inr[nt][r] += uu * vv; }
                    q[r] = f2bf(uu);
                }
                pU[c * 3 + nt] = q;
            }
        }
        #pragma unroll
        for (int nt = 0; nt < 3; ++nt) {
            #pragma unroll
            for (int r = 0; r < 4; ++r) {
                int row = nt * 16 + (kp << 2) + r;
                SH[A2B + row * A2S + 128 + col] = f2bf(nrm[nt][r]);
            }
        }

        // ---- cluster2: bW2 (asyncs have had all of stage1 to fly) ----
        bf16x8 bWs[4], bWt[4], bWv[4];
        #pragma unroll
        for (int ks = 0; ks < 4; ++ks) {
            int k0 = (ks << 5) + (kp << 3);
            if constexpr (PRE) {
                bWs[ks] = *(const bf16x8*)&wW2[(0 * F + col) * F + k0];
                bWt[ks] = *(const bf16x8*)&wW2[(1 * F + col) * F + k0];
                bWv[ks] = *(const bf16x8*)&wW2[(2 * F + col) * F + k0];
            } else {
                const float4* p0 = (const float4*)&aw2[(size_t)(0 * F + col) * F + k0];
                const float4* p1 = (const float4*)&aw2[(size_t)(1 * F + col) * F + k0];
                const float4* p2 = (const float4*)&aw2[(size_t)(2 * F + col) * F + k0];
                bWs[ks] = pack8(p0[0], p0[1]);
                bWt[ks] = pack8(p1[0], p1[1]);
                bWv[ks] = pack8(p2[0], p2[1]);
            }
        }
        asm volatile("s_waitcnt lgkmcnt(0)" ::: "memory");
        __builtin_amdgcn_s_barrier();       // B2: A2 complete

        // ---- stage 2: h = shifted_softplus(mlp_in @ w1.T + b1) (24 MFMAs) ----
        f32x4 accH[3];
        #pragma unroll
        for (int nt = 0; nt < 3; ++nt) accH[nt] = (f32x4){0.f,0.f,0.f,0.f};
        #pragma unroll
        for (int ks = 0; ks < 8; ++ks) {
            int k0 = (ks << 5) + (kp << 3);
            #pragma unroll
            for (int nt = 0; nt < 3; ++nt) {
                bf16x8 a = *(const bf16x8*)&SH[A2B + (nt * 16 + l15) * A2S + k0];
                accH[nt] = __builtin_amdgcn_mfma_f32_16x16x32_bf16(a, bW1[ks], accH[nt], 0, 0, 0);
            }
        }
        #pragma unroll
        for (int nt = 0; nt < 3; ++nt) {
            #pragma unroll
            for (int r = 0; r < 4; ++r) {
                float x = accH[nt][r] + b1;
                float hsp = fmaxf(x, 0.f) + __logf(1.f + __expf(-fabsf(x))) - 0.69314718056f;
                int row = nt * 16 + (kp << 2) + r;
                SH[A3B + row * A3S + col] = f2bf(hsp);
            }
        }
        asm volatile("s_waitcnt lgkmcnt(0)" ::: "memory");
        __builtin_amdgcn_s_barrier();       // B3: A3 ready

        // ---- stage 3: three output GEMMs (36 MFMAs) ----
        f32x4 accS[3], accT[3], accA[3];
        #pragma unroll
        for (int i = 0; i < 3; ++i) {
            accS[i] = (f32x4){0.f,0.f,0.f,0.f};
            accT[i] = (f32x4){0.f,0.f,0.f,0.f};
            accA[i] = (f32x4){0.f,0.f,0.f,0.f};
        }
        #pragma unroll
        for (int ks = 0; ks < 4; ++ks) {
            int k0 = (ks << 5) + (kp << 3);
            #pragma unroll
            for (int nt = 0; nt < 3; ++nt) {
                bf16x8 a = *(const bf16x8*)&SH[A3B + (nt * 16 + l15) * A3S + k0];
                accS[nt] = __builtin_amdgcn_mfma_f32_16x16x32_bf16(a, bWs[ks], accS[nt], 0, 0, 0);
                accT[nt] = __builtin_amdgcn_mfma_f32_16x16x32_bf16(a, bWt[ks], accT[nt], 0, 0, 0);
                accA[nt] = __builtin_amdgcn_mfma_f32_16x16x32_bf16(a, bWv[ks], accA[nt], 0, 0, 0);
            }
        }

        // ---- epilogue: v_new (dwordx3) and s_new; residuals from bf16 LDS ----
        #pragma unroll
        for (int nt = 0; nt < 3; ++nt) {
            #pragma unroll
            for (int r = 0; r < 4; ++r) {
                int nl = nt * 16 + (kp << 2) + r;
                int n  = t * TILE + nl;
                if (n < Ntot) {
                    float avv = accA[nt][r] + bvv;
                    size_t base = ((size_t)n * F + col) * 3;
                    f3 val;
                    val.x = bf2f(SH[vr_idx(0 * TILE + nl, col)]) + avv * bf2f(pU[0 * 3 + nt][r]);
                    val.y = bf2f(SH[vr_idx(1 * TILE + nl, col)]) + avv * bf2f(pU[1 * 3 + nt][r]);
                    val.z = bf2f(SH[vr_idx(2 * TILE + nl, col)]) + avv * bf2f(pU[2 * 3 + nt][r]);
                    *(f3*)&out[NF + base] = val;
                    float sres = bf2f(SH[A2B + nl * A2S + col]);
                    out[(size_t)n * F + col] = sres + (accS[nt][r] + bss) + (accT[nt][r] + bsv) * inr[nt][r];
                }
            }
        }
    }
}

extern "C" void kernel_launch(void* const* d_in, const int* in_sizes, int n_in,
                              void* d_out, int out_size, void* d_ws, size_t ws_size,
                              hipStream_t stream) {
    (void)n_in; (void)out_size;
    const float* s   = (const float*)d_in[0];
    const float* v   = (const float*)d_in[1];
    const float* Uw  = (const float*)d_in[2];
    const float* Vw  = (const float*)d_in[3];
    const float* aw1 = (const float*)d_in[4];
    const float* ab1 = (const float*)d_in[5];
    const float* aw2 = (const float*)d_in[6];
    const float* ab2 = (const float*)d_in[7];
    float* out = (float*)d_out;
    int Ntot = in_sizes[0] / F;                 // 100000

    if (ws_size >= 114688u * sizeof(unsigned short)) {
        unsigned short* wbf = (unsigned short*)d_ws;
        hipLaunchKernelGGL(prep_w, dim3(112), dim3(256), 0, stream, Uw, Vw, aw1, aw2, wbf);
        hipLaunchKernelGGL((painn_main<true>), dim3(NBLK), dim3(NTHR), 0, stream,
                           s, v, Uw, Vw, aw1, ab1, aw2, ab2, wbf, out, Ntot);
    } else {
        hipLaunchKernelGGL((painn_main<false>), dim3(NBLK), dim3(NTHR), 0, stream,
                           s, v, Uw, Vw, aw1, ab1, aw2, ab2, (const unsigned short*)nullptr, out, Ntot);
    }
}

// Round 9
// 206.307 us; speedup vs baseline: 2.0048x; 2.0048x over previous
//
#include <hip/hip_runtime.h>

#define F 128
#define TILE 32
#define NTHR 512

typedef __attribute__((ext_vector_type(8))) __bf16 bf16x8;
typedef __attribute__((ext_vector_type(4))) float f32x4;
typedef __attribute__((ext_vector_type(8))) unsigned short us8;
typedef __attribute__((ext_vector_type(4))) unsigned short us4;
typedef __attribute__((ext_vector_type(2))) unsigned short us2;
typedef unsigned short us;

struct f3 { float x, y, z; };   // 12B -> global_store_dwordx3

#define MFMA(a,b,c) __builtin_amdgcn_mfma_f32_16x16x32_bf16((a),(b),(c),0,0,0)

__device__ __forceinline__ us f2bf(float x) {
    __bf16 h = (__bf16)x;
    return __builtin_bit_cast(us, h);
}
__device__ __forceinline__ float bf2f(us u) {
    unsigned x = ((unsigned)u) << 16;
    return __builtin_bit_cast(float, x);
}
__device__ __forceinline__ bf16x8 pack8(float4 a, float4 b) {
    us8 t;
    t[0] = f2bf(a.x); t[1] = f2bf(a.y); t[2] = f2bf(a.z); t[3] = f2bf(a.w);
    t[4] = f2bf(b.x); t[5] = f2bf(b.y); t[6] = f2bf(b.z); t[7] = f2bf(b.w);
    return __builtin_bit_cast(bf16x8, t);
}
__device__ __forceinline__ void gload16(const float* g, const us* l) {
    __builtin_amdgcn_global_load_lds(
        (const __attribute__((address_space(1))) void*)g,
        (__attribute__((address_space(3))) void*)l, 16, 0, 0);
}
__device__ __forceinline__ void bar_lgkm() {
    asm volatile("s_waitcnt lgkmcnt(0)" ::: "memory");
    __builtin_amdgcn_s_barrier();
}

// ================= prep: weights f32 -> bf16 in ws =================
__global__ __launch_bounds__(256)
void prep_w(const float* __restrict__ Uw, const float* __restrict__ Vw,
            const float* __restrict__ aw1, const float* __restrict__ aw2,
            us* __restrict__ wbf)
{
    int i = (blockIdx.x * 256 + threadIdx.x) * 4;   // 112x256x4 = 114688
    const float* src; int off;
    if (i < 16384)      { src = Uw;  off = i; }
    else if (i < 32768) { src = Vw;  off = i - 16384; }
    else if (i < 65536) { src = aw1; off = i - 32768; }
    else                { src = aw2; off = i - 65536; }
    float4 x = *(const float4*)&src[off];
    us4 o;
    o[0] = f2bf(x.x); o[1] = f2bf(x.y); o[2] = f2bf(x.z); o[3] = f2bf(x.w);
    *(us4*)&wbf[i] = o;
}

// ================= K1/K3 shared LDS geometry =================
#define K_RAWV 0        // 24576 sh : raw f32 v tile (32x128x3)
#define K_VRB  24576    // 12288 sh : v bf16, 96 rows x 128, XOR-swizzled
#define K_OUT  24576    // overlay (after barrier): nrm 4096 | inr 4096
#define K_SHSZ 36864    // 73728 B -> 2 blocks/CU

__device__ __forceinline__ int k_vr(int crow, int k) {
    return K_VRB + (((crow << 7) + k) ^ ((crow & 7) << 3));
}

// stage+convert helper body (macro to keep identical codegen in k1/k3)
#define STAGE_AND_CONVERT(vptr, t)                                              \
    {                                                                           \
        const float* vsrc = (vptr) + (size_t)(t) * (TILE * 384);                \
        _Pragma("unroll")                                                       \
        for (int j = 0; j < 6; ++j) {                                           \
            int ofs = (w + j * 8) * 256;                                        \
            gload16(vsrc + ofs + lane * 4, &SH[K_RAWV + ofs * 2]);              \
        }                                                                       \
    }                                                                           \
    asm volatile("s_waitcnt vmcnt(0)" ::: "memory");                            \
    __builtin_amdgcn_s_barrier();                                               \
    {                                                                           \
        const float* rawv = (const float*)&SH[K_RAWV];                          \
        _Pragma("unroll")                                                       \
        for (int it = 0; it < 4; ++it) {                                        \
            int idx = tid + it * 512, nl = idx >> 6, f0 = (idx & 63) << 1;      \
            const float2* src = (const float2*)&rawv[nl * 384 + f0 * 3];        \
            float2 ab = src[0], cd = src[1], ef = src[2];                       \
            us2 p;                                                              \
            p[0]=f2bf(ab.x); p[1]=f2bf(cd.y); *(us2*)&SH[k_vr(0*TILE+nl,f0)]=p; \
            p[0]=f2bf(ab.y); p[1]=f2bf(ef.x); *(us2*)&SH[k_vr(1*TILE+nl,f0)]=p; \
            p[0]=f2bf(cd.x); p[1]=f2bf(ef.y); *(us2*)&SH[k_vr(2*TILE+nl,f0)]=p; \
        }                                                                       \
    }                                                                           \
    bar_lgkm();

// ================= K1: Uv,Vv -> nrm(bf16), inner(bf16) =================
__global__ __launch_bounds__(NTHR, 4)
void k1_uv(const float* __restrict__ v, const us* __restrict__ wbf,
           us* __restrict__ wnrm, us* __restrict__ winr, int Ntot)
{
    __shared__ __align__(16) us SH[K_SHSZ];
    const int tid = threadIdx.x, lane = tid & 63, w = tid >> 6;
    const int l15 = lane & 15, kp = lane >> 4;
    const int col = (w << 4) | l15;
    const int t   = blockIdx.x;

    STAGE_AND_CONVERT(v, t)

    bf16x8 bU[4], bV[4];
    #pragma unroll
    for (int ks = 0; ks < 4; ++ks) {
        int k0 = (ks << 5) + (kp << 3);
        bU[ks] = *(const bf16x8*)&wbf[col * F + k0];
        bV[ks] = *(const bf16x8*)&wbf[16384 + col * F + k0];
    }
    float nrm[2][4], inr[2][4];
    #pragma unroll
    for (int c = 0; c < 3; ++c) {
        f32x4 aU[2], aV[2];
        aU[0]=(f32x4){0,0,0,0}; aU[1]=(f32x4){0,0,0,0};
        aV[0]=(f32x4){0,0,0,0}; aV[1]=(f32x4){0,0,0,0};
        #pragma unroll
        for (int ks = 0; ks < 4; ++ks) {
            #pragma unroll
            for (int nt = 0; nt < 2; ++nt) {
                bf16x8 a = *(const bf16x8*)&SH[k_vr(c*TILE + nt*16 + l15, (ks<<5)+(kp<<3))];
                aU[nt] = MFMA(a, bU[ks], aU[nt]);
                aV[nt] = MFMA(a, bV[ks], aV[nt]);
            }
        }
        #pragma unroll
        for (int nt = 0; nt < 2; ++nt)
            #pragma unroll
            for (int r = 0; r < 4; ++r) {
                float uu = aU[nt][r], vv = aV[nt][r];
                if (c == 0) { nrm[nt][r] = vv*vv; inr[nt][r] = uu*vv; }
                else        { nrm[nt][r] += vv*vv; inr[nt][r] += uu*vv; }
            }
    }
    bar_lgkm();   // all VR reads done; overlay OUT
    #pragma unroll
    for (int nt = 0; nt < 2; ++nt)
        #pragma unroll
        for (int r = 0; r < 4; ++r) {
            int row = nt * 16 + (kp << 2) + r;
            SH[K_OUT + row * 128 + col]        = f2bf(nrm[nt][r]);
            SH[K_OUT + 4096 + row * 128 + col] = f2bf(inr[nt][r]);
        }
    bar_lgkm();
    // linear coalesced stores (16B/lane)
    *(us8*)&wnrm[(size_t)t * 4096 + tid * 8] = *(const us8*)&SH[K_OUT + tid * 8];
    *(us8*)&winr[(size_t)t * 4096 + tid * 8] = *(const us8*)&SH[K_OUT + 4096 + tid * 8];
}

// ================= K2: MLP -> s_new, avv(bf16, bias folded) =================
#define M_A2S 264
#define M_A3B 8448
#define M_A3S 136
#define M_SHSZ 12800

__global__ __launch_bounds__(NTHR, 4)
void k2_mlp(const float* __restrict__ s, const us* __restrict__ wbf,
            const float* __restrict__ ab1, const float* __restrict__ ab2,
            const us* __restrict__ wnrm, const us* __restrict__ winr,
            us* __restrict__ wavv, float* __restrict__ out, int Ntot)
{
    __shared__ __align__(16) us SH[M_SHSZ];
    const int tid = threadIdx.x, lane = tid & 63, w = tid >> 6;
    const int l15 = lane & 15, kp = lane >> 4;
    const int col = (w << 4) | l15;
    const int t   = blockIdx.x;
    const int srow = tid >> 4, sf0 = (tid & 15) << 3;

    // stage A2 = [s bf16 | nrm bf16]
    {
        const float4* sp = (const float4*)&s[(size_t)t * TILE * 128 + srow * 128 + sf0];
        float4 x = sp[0], y = sp[1];
        us4 t0, t1;
        t0[0]=f2bf(x.x); t0[1]=f2bf(x.y); t0[2]=f2bf(x.z); t0[3]=f2bf(x.w);
        t1[0]=f2bf(y.x); t1[1]=f2bf(y.y); t1[2]=f2bf(y.z); t1[3]=f2bf(y.w);
        *(us4*)&SH[srow * M_A2S + sf0]     = t0;
        *(us4*)&SH[srow * M_A2S + sf0 + 4] = t1;
        us8 nv = *(const us8*)&wnrm[(size_t)t * 4096 + tid * 8];
        *(us8*)&SH[srow * M_A2S + 128 + sf0] = nv;
    }
    bar_lgkm();

    // stage 2: h = shifted_softplus(mlp_in @ w1.T + b1)
    f32x4 accH[2];
    accH[0]=(f32x4){0,0,0,0}; accH[1]=(f32x4){0,0,0,0};
    #pragma unroll
    for (int ks = 0; ks < 8; ++ks) {
        int k0 = (ks << 5) + (kp << 3);
        bf16x8 bw = *(const bf16x8*)&wbf[32768 + col * 256 + k0];
        #pragma unroll
        for (int nt = 0; nt < 2; ++nt) {
            bf16x8 a = *(const bf16x8*)&SH[(nt * 16 + l15) * M_A2S + k0];
            accH[nt] = MFMA(a, bw, accH[nt]);
        }
    }
    float b1 = ab1[col];
    #pragma unroll
    for (int nt = 0; nt < 2; ++nt)
        #pragma unroll
        for (int r = 0; r < 4; ++r) {
            float x = accH[nt][r] + b1;
            float hsp = fmaxf(x, 0.f) + __logf(1.f + __expf(-fabsf(x))) - 0.69314718056f;
            int row = nt * 16 + (kp << 2) + r;
            SH[M_A3B + row * M_A3S + col] = f2bf(hsp);
        }
    bar_lgkm();

    // stage 3: three output GEMMs
    f32x4 accS[2], accT[2], accA[2];
    #pragma unroll
    for (int i = 0; i < 2; ++i) {
        accS[i]=(f32x4){0,0,0,0}; accT[i]=(f32x4){0,0,0,0}; accA[i]=(f32x4){0,0,0,0};
    }
    #pragma unroll
    for (int ks = 0; ks < 4; ++ks) {
        int k0 = (ks << 5) + (kp << 3);
        bf16x8 bws = *(const bf16x8*)&wbf[65536 + (0 * F + col) * F + k0];
        bf16x8 bwt = *(const bf16x8*)&wbf[65536 + (1 * F + col) * F + k0];
        bf16x8 bwv = *(const bf16x8*)&wbf[65536 + (2 * F + col) * F + k0];
        #pragma unroll
        for (int nt = 0; nt < 2; ++nt) {
            bf16x8 a = *(const bf16x8*)&SH[M_A3B + (nt * 16 + l15) * M_A3S + k0];
            accS[nt] = MFMA(a, bws, accS[nt]);
            accT[nt] = MFMA(a, bwt, accT[nt]);
            accA[nt] = MFMA(a, bwv, accA[nt]);
        }
    }

    // epilogue: s_new (f32, coalesced 64B/quarter-wave)
    float bss = ab2[col], bsv = ab2[F + col], bvv = ab2[2 * F + col];
    #pragma unroll
    for (int nt = 0; nt < 2; ++nt)
        #pragma unroll
        for (int r = 0; r < 4; ++r) {
            int nl = nt * 16 + (kp << 2) + r;
            size_t n = (size_t)t * TILE + nl;
            float inner = bf2f(winr[n * 128 + col]);
            float sres  = bf2f(SH[nl * M_A2S + col]);
            out[n * 128 + col] = sres + (accS[nt][r] + bss) + (accT[nt][r] + bsv) * inner;
        }
    bar_lgkm();   // A2/A3 reads done; overlay avv at base 0
    #pragma unroll
    for (int nt = 0; nt < 2; ++nt)
        #pragma unroll
        for (int r = 0; r < 4; ++r) {
            int row = nt * 16 + (kp << 2) + r;
            SH[row * 128 + col] = f2bf(accA[nt][r] + bvv);
        }
    bar_lgkm();
    *(us8*)&wavv[(size_t)t * 4096 + tid * 8] = *(const us8*)&SH[tid * 8];
}

// ================= K3: recompute Uv -> v_new (residual from raw f32) =========
__global__ __launch_bounds__(NTHR, 4)
void k3_vnew(const float* __restrict__ v, const us* __restrict__ wbf,
             const us* __restrict__ wavv, float* __restrict__ out, int Ntot)
{
    __shared__ __align__(16) us SH[K_SHSZ];
    const int tid = threadIdx.x, lane = tid & 63, w = tid >> 6;
    const int l15 = lane & 15, kp = lane >> 4;
    const int col = (w << 4) | l15;
    const int t   = blockIdx.x;
    const size_t NF = (size_t)Ntot * F;

    STAGE_AND_CONVERT(v, t)

    bf16x8 bU[4];
    #pragma unroll
    for (int ks = 0; ks < 4; ++ks) {
        int k0 = (ks << 5) + (kp << 3);
        bU[ks] = *(const bf16x8*)&wbf[col * F + k0];
    }
    us4 pU[3][2];
    #pragma unroll
    for (int c = 0; c < 3; ++c) {
        f32x4 aU[2];
        aU[0]=(f32x4){0,0,0,0}; aU[1]=(f32x4){0,0,0,0};
        #pragma unroll
        for (int ks = 0; ks < 4; ++ks) {
            #pragma unroll
            for (int nt = 0; nt < 2; ++nt) {
                bf16x8 a = *(const bf16x8*)&SH[k_vr(c*TILE + nt*16 + l15, (ks<<5)+(kp<<3))];
                aU[nt] = MFMA(a, bU[ks], aU[nt]);
            }
        }
        #pragma unroll
        for (int nt = 0; nt < 2; ++nt) {
            us4 q;
            #pragma unroll
            for (int r = 0; r < 4; ++r) q[r] = f2bf(aU[nt][r]);
            pU[c][nt] = q;
        }
    }

    const float* rawv = (const float*)&SH[K_RAWV];   // still valid (never overwritten)
    #pragma unroll
    for (int nt = 0; nt < 2; ++nt)
        #pragma unroll
        for (int r = 0; r < 4; ++r) {
            int nl = nt * 16 + (kp << 2) + r;
            size_t n = (size_t)t * TILE + nl;
            float avv = bf2f(wavv[n * 128 + col]);
            f3 val;
            val.x = rawv[nl * 384 + col * 3 + 0] + avv * bf2f(pU[0][nt][r]);
            val.y = rawv[nl * 384 + col * 3 + 1] + avv * bf2f(pU[1][nt][r]);
            val.z = rawv[nl * 384 + col * 3 + 2] + avv * bf2f(pU[2][nt][r]);
            *(f3*)&out[NF + (n * 128 + col) * 3] = val;
        }
}

// ================= fallback: fused persistent kernel (R5, 187us proven) ======
#define FD_RAWV 0
#define FD_A1B  24576
#define FD_A1S  136
#define FD_A2B  37632
#define FD_A2S  264
#define FD_A3B  46080
#define FD_A3S  136
#define FD_SHSZ 50432
#define FD_NBLK 256

template<bool PRE>
__global__ __launch_bounds__(NTHR) __attribute__((amdgpu_waves_per_eu(2, 2)))
void fused_fb(const float* __restrict__ s, const float* __restrict__ v,
              const float* __restrict__ Uw, const float* __restrict__ Vw,
              const float* __restrict__ aw1, const float* __restrict__ ab1,
              const float* __restrict__ aw2, const float* __restrict__ ab2,
              const us* __restrict__ wbf, float* __restrict__ out, int Ntot)
{
    __shared__ __align__(16) us SH[FD_SHSZ];
    const int tid = threadIdx.x, lane = tid & 63, w = tid >> 6;
    const int l15 = lane & 15, kp = lane >> 4;
    const int col = (w << 4) | l15;
    const size_t NF = (size_t)Ntot * F;
    const int NT = Ntot / TILE;
    const us* wU  = wbf;
    const us* wV  = wbf + 16384;
    const us* wW1 = wbf + 32768;
    const us* wW2 = wbf + 65536;
    const float b1 = ab1[col], bss = ab2[col], bsv = ab2[F+col], bvv = ab2[2*F+col];
    const int srow = tid >> 4, sf0 = (tid & 15) << 3;
    const float* rawv = (const float*)&SH[FD_RAWV];
    float4 sp0, sp1;
    {
        int t0 = blockIdx.x;
        const float* vsrc = v + (size_t)t0 * TILE * 384;
        #pragma unroll
        for (int j = 0; j < 6; ++j) {
            int ofs = (w + j * 8) * 256;
            gload16(vsrc + ofs + lane * 4, &SH[FD_RAWV + ofs * 2]);
        }
        const float* ssrc = s + (size_t)t0 * TILE * 128 + srow * 128 + sf0;
        sp0 = *(const float4*)ssrc; sp1 = *(const float4*)(ssrc + 4);
    }
    asm volatile("s_waitcnt vmcnt(0)" ::: "memory");
    for (int t = blockIdx.x; t < NT; t += FD_NBLK) {
        asm volatile("s_waitcnt vmcnt(8)" ::: "memory");
        __builtin_amdgcn_s_barrier();
        bf16x8 bU[4], bV[4], bW1[8], bWs[4], bWt[4], bWv[4];
        if constexpr (PRE) {
            #pragma unroll
            for (int ks = 0; ks < 4; ++ks) {
                int k0 = (ks << 5) + (kp << 3);
                bU[ks] = *(const bf16x8*)&wU[col*F+k0];
                bV[ks] = *(const bf16x8*)&wV[col*F+k0];
                bWs[ks] = *(const bf16x8*)&wW2[(0*F+col)*F+k0];
                bWt[ks] = *(const bf16x8*)&wW2[(1*F+col)*F+k0];
                bWv[ks] = *(const bf16x8*)&wW2[(2*F+col)*F+k0];
            }
            #pragma unroll
            for (int ks = 0; ks < 8; ++ks)
                bW1[ks] = *(const bf16x8*)&wW1[col*256 + (ks<<5)+(kp<<3)];
        } else {
            #pragma unroll
            for (int ks = 0; ks < 4; ++ks) {
                int k0 = (ks << 5) + (kp << 3);
                const float4* p;
                p = (const float4*)&Uw[col*F+k0];               bU[ks]=pack8(p[0],p[1]);
                p = (const float4*)&Vw[col*F+k0];               bV[ks]=pack8(p[0],p[1]);
                p = (const float4*)&aw2[(size_t)(0*F+col)*F+k0]; bWs[ks]=pack8(p[0],p[1]);
                p = (const float4*)&aw2[(size_t)(1*F+col)*F+k0]; bWt[ks]=pack8(p[0],p[1]);
                p = (const float4*)&aw2[(size_t)(2*F+col)*F+k0]; bWv[ks]=pack8(p[0],p[1]);
            }
            #pragma unroll
            for (int ks = 0; ks < 8; ++ks) {
                const float4* p = (const float4*)&aw1[col*256 + (ks<<5)+(kp<<3)];
                bW1[ks] = pack8(p[0], p[1]);
            }
        }
        __builtin_amdgcn_sched_barrier(0);
        #pragma unroll
        for (int it = 0; it < 4; ++it) {
            int nl = w + (it << 3);
            const float2* src = (const float2*)&rawv[nl * 384 + (lane << 1) * 3];
            float2 ab = src[0], cd = src[1], ef = src[2];
            int vf0 = lane << 1;
            us2 p;
            p[0]=f2bf(ab.x); p[1]=f2bf(cd.y); *(us2*)&SH[FD_A1B+(0*TILE+nl)*FD_A1S+vf0]=p;
            p[0]=f2bf(ab.y); p[1]=f2bf(ef.x); *(us2*)&SH[FD_A1B+(1*TILE+nl)*FD_A1S+vf0]=p;
            p[0]=f2bf(cd.x); p[1]=f2bf(ef.y); *(us2*)&SH[FD_A1B+(2*TILE+nl)*FD_A1S+vf0]=p;
        }
        {
            us4 t0, t1;
            t0[0]=f2bf(sp0.x); t0[1]=f2bf(sp0.y); t0[2]=f2bf(sp0.z); t0[3]=f2bf(sp0.w);
            t1[0]=f2bf(sp1.x); t1[1]=f2bf(sp1.y); t1[2]=f2bf(sp1.z); t1[3]=f2bf(sp1.w);
            *(us4*)&SH[FD_A2B + srow*FD_A2S + sf0]     = t0;
            *(us4*)&SH[FD_A2B + srow*FD_A2S + sf0 + 4] = t1;
        }
        bar_lgkm();
        if (t + FD_NBLK < NT) {
            int t2 = t + FD_NBLK;
            const float* vsrc = v + (size_t)t2 * TILE * 384;
            #pragma unroll
            for (int j = 0; j < 6; ++j) {
                int ofs = (w + j * 8) * 256;
                gload16(vsrc + ofs + lane * 4, &SH[FD_RAWV + ofs * 2]);
            }
            const float* ssrc = s + (size_t)t2 * TILE * 128 + srow * 128 + sf0;
            sp0 = *(const float4*)ssrc; sp1 = *(const float4*)(ssrc + 4);
        }
        __builtin_amdgcn_sched_barrier(0);
        float inr[2][4], nrm[2][4];
        us4 pU[6];
        #pragma unroll
        for (int c = 0; c < 3; ++c) {
            f32x4 aU[2], aV[2];
            aU[0]=(f32x4){0,0,0,0}; aU[1]=(f32x4){0,0,0,0};
            aV[0]=(f32x4){0,0,0,0}; aV[1]=(f32x4){0,0,0,0};
            #pragma unroll
            for (int ks = 0; ks < 4; ++ks) {
                #pragma unroll
                for (int nt = 0; nt < 2; ++nt) {
                    bf16x8 a = *(const bf16x8*)&SH[FD_A1B + ((c*2+nt)*16 + l15)*FD_A1S + (ks<<5)+(kp<<3)];
                    aU[nt] = MFMA(a, bU[ks], aU[nt]);
                    aV[nt] = MFMA(a, bV[ks], aV[nt]);
                }
            }
            #pragma unroll
            for (int nt = 0; nt < 2; ++nt) {
                us4 q;
                #pragma unroll
                for (int r = 0; r < 4; ++r) {
                    float uu = aU[nt][r], vv = aV[nt][r];
                    if (c == 0) { nrm[nt][r]=vv*vv; inr[nt][r]=uu*vv; }
                    else        { nrm[nt][r]+=vv*vv; inr[nt][r]+=uu*vv; }
                    q[r] = f2bf(uu);
                }
                pU[c*2+nt] = q;
            }
        }
        #pragma unroll
        for (int nt = 0; nt < 2; ++nt)
            #pragma unroll
            for (int r = 0; r < 4; ++r)
                SH[FD_A2B + (nt*16+(kp<<2)+r)*FD_A2S + 128 + col] = f2bf(nrm[nt][r]);
        bar_lgkm();
        f32x4 accH[2];
        accH[0]=(f32x4){0,0,0,0}; accH[1]=(f32x4){0,0,0,0};
        #pragma unroll
        for (int ks = 0; ks < 8; ++ks) {
            int k0 = (ks << 5) + (kp << 3);
            #pragma unroll
            for (int nt = 0; nt < 2; ++nt) {
                bf16x8 a = *(const bf16x8*)&SH[FD_A2B + (nt*16+l15)*FD_A2S + k0];
                accH[nt] = MFMA(a, bW1[ks], accH[nt]);
            }
        }
        #pragma unroll
        for (int nt = 0; nt < 2; ++nt)
            #pragma unroll
            for (int r = 0; r < 4; ++r) {
                float x = accH[nt][r] + b1;
                float hsp = fmaxf(x, 0.f) + __logf(1.f + __expf(-fabsf(x))) - 0.69314718056f;
                SH[FD_A3B + (nt*16+(kp<<2)+r)*FD_A3S + col] = f2bf(hsp);
            }
        bar_lgkm();
        f32x4 accS[2], accT[2], accA[2];
        #pragma unroll
        for (int i = 0; i < 2; ++i) {
            accS[i]=(f32x4){0,0,0,0}; accT[i]=(f32x4){0,0,0,0}; accA[i]=(f32x4){0,0,0,0};
        }
        #pragma unroll
        for (int ks = 0; ks < 4; ++ks) {
            int k0 = (ks << 5) + (kp << 3);
            #pragma unroll
            for (int nt = 0; nt < 2; ++nt) {
                bf16x8 a = *(const bf16x8*)&SH[FD_A3B + (nt*16+l15)*FD_A3S + k0];
                accS[nt] = MFMA(a, bWs[ks], accS[nt]);
                accT[nt] = MFMA(a, bWt[ks], accT[nt]);
                accA[nt] = MFMA(a, bWv[ks], accA[nt]);
            }
        }
        #pragma unroll
        for (int nt = 0; nt < 2; ++nt)
            #pragma unroll
            for (int r = 0; r < 4; ++r) {
                int nl = nt*16 + (kp<<2) + r;
                int n  = t * TILE + nl;
                float avv = accA[nt][r] + bvv;
                size_t base = ((size_t)n * F + col) * 3;
                f3 val;
                val.x = bf2f(SH[FD_A1B+(0*TILE+nl)*FD_A1S+col]) + avv*bf2f(pU[0*2+nt][r]);
                val.y = bf2f(SH[FD_A1B+(1*TILE+nl)*FD_A1S+col]) + avv*bf2f(pU[1*2+nt][r]);
                val.z = bf2f(SH[FD_A1B+(2*TILE+nl)*FD_A1S+col]) + avv*bf2f(pU[2*2+nt][r]);
                *(f3*)&out[NF + base] = val;
                float sres = bf2f(SH[FD_A2B + nl*FD_A2S + col]);
                out[(size_t)n*F + col] = sres + (accS[nt][r]+bss) + (accT[nt][r]+bsv)*inr[nt][r];
            }
    }
}

extern "C" void kernel_launch(void* const* d_in, const int* in_sizes, int n_in,
                              void* d_out, int out_size, void* d_ws, size_t ws_size,
                              hipStream_t stream) {
    (void)n_in; (void)out_size;
    const float* s   = (const float*)d_in[0];
    const float* v   = (const float*)d_in[1];
    const float* Uw  = (const float*)d_in[2];
    const float* Vw  = (const float*)d_in[3];
    const float* aw1 = (const float*)d_in[4];
    const float* ab1 = (const float*)d_in[5];
    const float* aw2 = (const float*)d_in[6];
    const float* ab2 = (const float*)d_in[7];
    float* out = (float*)d_out;
    int Ntot = in_sizes[0] / F;                 // 100000 (divisible by 32)
    int NTb  = Ntot / TILE;                     // 3125

    const size_t WSZ_W = 114688ull * 2;         // bf16 weights
    const size_t PER   = (size_t)Ntot * F * 2;  // one bf16 intermediate

    if (ws_size >= WSZ_W + 3 * PER) {
        us* wbf  = (us*)d_ws;
        us* wnrm = (us*)((char*)d_ws + WSZ_W);
        us* winr = wnrm + (size_t)Ntot * F;
        us* wavv = winr + (size_t)Ntot * F;
        hipLaunchKernelGGL(prep_w, dim3(112), dim3(256), 0, stream, Uw, Vw, aw1, aw2, wbf);
        hipLaunchKernelGGL(k1_uv,   dim3(NTb), dim3(NTHR), 0, stream, v, wbf, wnrm, winr, Ntot);
        hipLaunchKernelGGL(k2_mlp,  dim3(NTb), dim3(NTHR), 0, stream, s, wbf, ab1, ab2, wnrm, winr, wavv, out, Ntot);
        hipLaunchKernelGGL(k3_vnew, dim3(NTb), dim3(NTHR), 0, stream, v, wbf, wavv, out, Ntot);
    } else if (ws_size >= WSZ_W) {
        us* wbf = (us*)d_ws;
        hipLaunchKernelGGL(prep_w, dim3(112), dim3(256), 0, stream, Uw, Vw, aw1, aw2, wbf);
        hipLaunchKernelGGL((fused_fb<true>), dim3(FD_NBLK), dim3(NTHR), 0, stream,
                           s, v, Uw, Vw, aw1, ab1, aw2, ab2, wbf, out, Ntot);
    } else {
        hipLaunchKernelGGL((fused_fb<false>), dim3(FD_NBLK), dim3(NTHR), 0, stream,
                           s, v, Uw, Vw, aw1, ab1, aw2, ab2, (const us*)nullptr, out, Ntot);
    }
}